// Round 3
// baseline (295.242 us; speedup 1.0000x reference)
//
#include <hip/hip_runtime.h>

#define NB 4
#define LQ 512
#define LK 512
#define EE 128
#define DD 256
#define GRID_BLOCKS 256

// Barrier slots: two single-use counters in dead space of the attn output.
// P2 = last attn element (skipped during phase A, fixed up after barrier 2).
// P1 = attn element 65 floats earlier (different cache line); it is only used
// at barrier 1 (before ANY attn write), then overwritten normally in phase A.
#define P2_IDX ((size_t)NB * LK * LQ - 1)
#define P1_IDX ((size_t)NB * LK * LQ - 66)

__device__ __forceinline__ float fast_rcp(float x) { return __builtin_amdgcn_rcpf(x); }

// Single-use grid barrier (counter must be 0 on entry; ends at GRID_BLOCKS).
// All 256 blocks are co-resident: LDS ~100 KB forces 1 block/CU, grid == #CUs.
__device__ __forceinline__ void grid_sync_once(unsigned* cnt) {
    __threadfence();                       // publish my global writes (agent scope)
    __syncthreads();                       // whole block done + fenced
    if (threadIdx.x == 0) {
        unsigned prev = __hip_atomic_fetch_add(cnt, 1u, __ATOMIC_ACQ_REL,
                                               __HIP_MEMORY_SCOPE_AGENT);
        if (prev != (unsigned)(GRID_BLOCKS - 1)) {
            while (__hip_atomic_load(cnt, __ATOMIC_ACQUIRE,
                                     __HIP_MEMORY_SCOPE_AGENT) < (unsigned)GRID_BLOCKS) {}
        }
    }
    __syncthreads();
    __threadfence();                       // order subsequent reads
}

__global__ __launch_bounds__(64) void init_barriers(float* attn) {
    if (threadIdx.x == 0) {
        ((unsigned*)attn)[P1_IDX] = 0u;
        ((unsigned*)attn)[P2_IDX] = 0u;
    }
}

// ONE persistent kernel, 256 blocks x 512 threads, 3 phases:
//  P0: projections  (16 rows/block; blocks 0..127 = query@Wc1 -> EqT transposed,
//      blocks 128..255 = key@Wc2 -> Ek row-major)          [writes ctx region]
//  -- grid barrier (P1) --
//  PA: scores+softmax for 8 l-rows (b = bid>>6, lt = bid&63) [reads ctx region,
//      writes attn + sj_s in LDS]
//  -- grid barrier (P2): all EqT/Ek reads complete --
//  PB: context for the same 8 rows from sj_s (LDS) + value   [overwrites ctx]
__global__ __launch_bounds__(512) void fused_atten_kernel(
    const float* __restrict__ query, const float* __restrict__ key,
    const float* __restrict__ value,
    const float* __restrict__ Wc1,  const float* __restrict__ Wc2,
    const float* __restrict__ vc,
    float* __restrict__ EqT, float* __restrict__ Ek,
    float* __restrict__ attn, float* __restrict__ ctx)
{
    __shared__ float in_s[16][DD];                       // 16 KB  (phase 0)
    __shared__ float ek_s[8][EE];                        // 4 KB
    __shared__ float vc_s[EE];                           // 0.5 KB
    __shared__ __align__(16) float s2p_s[4][8][LQ];      // 64 KB (PA partials; PB reduce)
    __shared__ float sj_s[8][LQ];                        // 16 KB (scaled P for PB)

    const int tid = threadIdx.x;

    // ================= Phase 0: projections =================
    {
        const int bid  = blockIdx.x;
        const bool is_q = (bid < 128);
        const int r0   = (is_q ? bid : bid - 128) * 16;   // first of 16 rows
        const float* src = is_q ? query : key;
        const float* W   = is_q ? Wc1   : Wc2;

        const float4* srow4 = (const float4*)(src + (size_t)r0 * DD);
        #pragma unroll
        for (int i = 0; i < 2; ++i)
            ((float4*)in_s)[i * 512 + tid] = srow4[i * 512 + tid];
        __syncthreads();

        const int c  = tid & 127;
        const int rg = tid >> 7;                          // 0..3 (wave-uniform)
        float acc[4] = {0.f, 0.f, 0.f, 0.f};
        for (int d = 0; d < DD; d += 8) {
            const float w0 = W[(d + 0) * EE + c];
            const float w1 = W[(d + 1) * EE + c];
            const float w2 = W[(d + 2) * EE + c];
            const float w3 = W[(d + 3) * EE + c];
            const float w4 = W[(d + 4) * EE + c];
            const float w5 = W[(d + 5) * EE + c];
            const float w6 = W[(d + 6) * EE + c];
            const float w7 = W[(d + 7) * EE + c];
            #pragma unroll
            for (int i = 0; i < 4; ++i) {
                const float4 xa = *(const float4*)&in_s[rg * 4 + i][d];
                const float4 xb = *(const float4*)&in_s[rg * 4 + i][d + 4];
                acc[i] += xa.x * w0 + xa.y * w1 + xa.z * w2 + xa.w * w3
                        + xb.x * w4 + xb.y * w5 + xb.z * w6 + xb.w * w7;
            }
        }
        if (is_q) {
            const int grow = r0 + rg * 4;                 // 16-row block never straddles b
            const int b    = grow >> 9;
            const int qloc = grow & 511;
            float4 o;
            o.x = __expf(2.0f * acc[0]); o.y = __expf(2.0f * acc[1]);
            o.z = __expf(2.0f * acc[2]); o.w = __expf(2.0f * acc[3]);
            *(float4*)&EqT[((size_t)(b * EE + c)) * LQ + qloc] = o;
        } else {
            #pragma unroll
            for (int i = 0; i < 4; ++i)
                Ek[(size_t)(r0 + rg * 4 + i) * EE + c] = __expf(2.0f * acc[i]);
        }
    }
    grid_sync_once((unsigned*)attn + P1_IDX);

    // ================= Phase A: scores + softmax =================
    const int b  = blockIdx.x >> 6;
    const int lt = blockIdx.x & 63;
    const int l0 = lt * 8;
    {
        const float* ekb = Ek + ((size_t)b * LK + l0) * EE;   // 1024 floats
        ((float*)ek_s)[tid]       = ekb[tid];
        ((float*)ek_s)[tid + 512] = ekb[tid + 512];
        if (tid < EE) vc_s[tid] = vc[tid];
    }
    __syncthreads();

    float vcsum = 0.f;
    #pragma unroll
    for (int e = 0; e < EE; e += 4) {
        const float4 v = *(const float4*)&vc_s[e];
        vcsum += (v.x + v.y) + (v.z + v.w);
    }

    {
        const int qq = tid & 127;
        const int eg = tid >> 7;
        float s2[8][4];
        #pragma unroll
        for (int l = 0; l < 8; ++l)
            { s2[l][0]=0.f; s2[l][1]=0.f; s2[l][2]=0.f; s2[l][3]=0.f; }

        const float4* eq4 = (const float4*)(EqT + (size_t)b * EE * LQ);
        #pragma unroll 2
        for (int i = 0; i < 32; ++i) {
            const int e = eg * 32 + i;
            const float4 a  = eq4[(size_t)e * 128 + qq];   // coalesced float4
            const float  vv = vc_s[e];
            #pragma unroll
            for (int l = 0; l < 8; ++l) {
                const float kk = ek_s[l][e];               // LDS broadcast
                s2[l][0] += vv * fast_rcp(a.x * kk + 1.0f);
                s2[l][1] += vv * fast_rcp(a.y * kk + 1.0f);
                s2[l][2] += vv * fast_rcp(a.z * kk + 1.0f);
                s2[l][3] += vv * fast_rcp(a.w * kk + 1.0f);
            }
        }
        #pragma unroll
        for (int l = 0; l < 8; ++l)
            *(float4*)&s2p_s[eg][l][qq * 4] =
                make_float4(s2[l][0], s2[l][1], s2[l][2], s2[l][3]);
    }
    __syncthreads();

    // softmax: wave w owns full row l = w (512 q)
    const int w = tid >> 6, lane = tid & 63;
    {
        float sjv[8], ex[8];
        float m = -1e30f;
        #pragma unroll
        for (int i = 0; i < 8; ++i) {
            const int idx = lane + 64 * i;
            const float p = s2p_s[0][w][idx] + s2p_s[1][w][idx]
                          + s2p_s[2][w][idx] + s2p_s[3][w][idx];
            sjv[i] = vcsum - 2.0f * p;
            m = fmaxf(m, sjv[i]);
        }
        #pragma unroll
        for (int off = 32; off >= 1; off >>= 1) m = fmaxf(m, __shfl_xor(m, off));
        float Z = 0.f;
        #pragma unroll
        for (int i = 0; i < 8; ++i) { ex[i] = __expf(sjv[i] - m); Z += ex[i]; }
        #pragma unroll
        for (int off = 32; off >= 1; off >>= 1) Z += __shfl_xor(Z, off);
        const float rs = fast_rcp(Z);

        float* arow = attn + ((size_t)(b * LK + l0 + w)) * LQ;
        const bool p2owner = (blockIdx.x == GRID_BLOCKS - 1) && (tid == 511);
        float keep = 0.f;
        #pragma unroll
        for (int i = 0; i < 8; ++i) {
            const int idx = lane + 64 * i;
            const float v = ex[i] * rs;
            sj_s[w][idx] = v;
            if (p2owner && i == 7) keep = v;               // P2 slot: defer
            else                   arow[idx] = v;
        }
        grid_sync_once((unsigned*)attn + P2_IDX);          // all EqT/Ek reads done
        if (p2owner) arow[511] = keep;                     // fix up P2 slot
    }

    // ================= Phase B: context (ctx overwrites EqT/Ek region) =======
    {
        const int g = w;                                   // q-group 0..7
        const float4* v4 = (const float4*)(value + (size_t)b * LQ * DD);
        float4 ac[8];
        #pragma unroll
        for (int l = 0; l < 8; ++l) ac[l] = make_float4(0.f, 0.f, 0.f, 0.f);

        const int q0 = g * 64;
        for (int q = q0; q < q0 + 64; q += 4) {
            float4 a[8];
            #pragma unroll
            for (int l = 0; l < 8; ++l)
                a[l] = *(const float4*)&sj_s[l][q];        // LDS broadcast
            const float4 v0 = v4[(size_t)(q + 0) * 64 + lane];
            const float4 v1 = v4[(size_t)(q + 1) * 64 + lane];
            const float4 v2 = v4[(size_t)(q + 2) * 64 + lane];
            const float4 v3 = v4[(size_t)(q + 3) * 64 + lane];
            #pragma unroll
            for (int l = 0; l < 8; ++l) {
                ac[l].x += a[l].x * v0.x; ac[l].y += a[l].x * v0.y;
                ac[l].z += a[l].x * v0.z; ac[l].w += a[l].x * v0.w;
                ac[l].x += a[l].y * v1.x; ac[l].y += a[l].y * v1.y;
                ac[l].z += a[l].y * v1.z; ac[l].w += a[l].y * v1.w;
                ac[l].x += a[l].z * v2.x; ac[l].y += a[l].z * v2.y;
                ac[l].z += a[l].z * v2.z; ac[l].w += a[l].z * v2.w;
                ac[l].x += a[l].w * v3.x; ac[l].y += a[l].w * v3.y;
                ac[l].z += a[l].w * v3.z; ac[l].w += a[l].w * v3.w;
            }
        }

        // tree reduce 8 -> 4 -> 2 -> 1 (red aliases s2p_s, dead since softmax)
        float4 (*red)[8][64] = (float4 (*)[8][64])s2p_s;
        if (g >= 4) {
            #pragma unroll
            for (int l = 0; l < 8; ++l) red[g - 4][l][lane] = ac[l];
        }
        __syncthreads();
        if (g < 4) {
            #pragma unroll
            for (int l = 0; l < 8; ++l) {
                const float4 r = red[g][l][lane];
                ac[l].x += r.x; ac[l].y += r.y; ac[l].z += r.z; ac[l].w += r.w;
            }
        }
        __syncthreads();
        if (g == 2 || g == 3) {
            #pragma unroll
            for (int l = 0; l < 8; ++l) red[g - 2][l][lane] = ac[l];
        }
        __syncthreads();
        if (g < 2) {
            #pragma unroll
            for (int l = 0; l < 8; ++l) {
                const float4 r = red[g][l][lane];
                ac[l].x += r.x; ac[l].y += r.y; ac[l].z += r.z; ac[l].w += r.w;
            }
        }
        __syncthreads();
        if (g == 1) {
            #pragma unroll
            for (int l = 0; l < 8; ++l) red[0][l][lane] = ac[l];
        }
        __syncthreads();
        if (g == 0) {
            #pragma unroll
            for (int l = 0; l < 8; ++l) {
                const float4 r = red[0][l][lane];
                ac[l].x += r.x; ac[l].y += r.y; ac[l].z += r.z; ac[l].w += r.w;
                ((float4*)ctx)[(size_t)(b * LK + l0 + l) * 64 + lane] = ac[l];
            }
        }
    }
}

extern "C" void kernel_launch(void* const* d_in, const int* in_sizes, int n_in,
                              void* d_out, int out_size, void* d_ws, size_t ws_size,
                              hipStream_t stream) {
    const float* query = (const float*)d_in[0];
    const float* key   = (const float*)d_in[1];
    const float* value = (const float*)d_in[2];
    const float* Wc1   = (const float*)d_in[3];
    const float* Wc2   = (const float*)d_in[4];
    const float* vc    = (const float*)d_in[5];

    float* ctx  = (float*)d_out;                          // [B, Lk, D]   = 524288 floats
    float* attn = (float*)d_out + (size_t)NB * LK * DD;   // [B, Lk, Lq]  = 1048576 floats

    // EqT/Ek scratch aliases the ctx region (exactly 2*NB*LQ*EE floats).
    // Safe: grid barrier 2 guarantees all EqT/Ek reads complete before the
    // context phase overwrites the region. d_ws is NOT used (prior session:
    // its re-poison races the timed stream).
    float* EqT = ctx;                                     // [B, E, Lq]
    float* Ek  = ctx + (size_t)NB * LQ * EE;              // [B, Lk, E]

    init_barriers<<<dim3(1), dim3(64), 0, stream>>>(attn);
    fused_atten_kernel<<<dim3(GRID_BLOCKS), dim3(512), 0, stream>>>(
        query, key, value, Wc1, Wc2, vc, EqT, Ek, attn, ctx);
}